// Round 4
// baseline (215.429 us; speedup 1.0000x reference)
//
#include <hip/hip_runtime.h>
#include <stdint.h>

typedef __bf16 bf16;
typedef __bf16 bf16x4 __attribute__((ext_vector_type(4)));
typedef __bf16 bf16x8 __attribute__((ext_vector_type(8)));
typedef float f32x4 __attribute__((ext_vector_type(4)));

#define MFMA(a, b, c) __builtin_amdgcn_mfma_f32_16x16x32_bf16(a, b, c, 0, 0, 0)

// ---------------- prep kernels ----------------

__global__ void k_cast_x(const float* __restrict__ x, bf16* __restrict__ xb) {
    int i = (blockIdx.x * 256 + threadIdx.x) * 4;
    float4 v = *reinterpret_cast<const float4*>(x + i);
    bf16x4 o = { (bf16)v.x, (bf16)v.y, (bf16)v.z, (bf16)v.w };
    *reinterpret_cast<bf16x4*>(xb + i) = o;
}

__global__ void k_prep_w(const float* __restrict__ w0, const float* __restrict__ w1,
                         const float* __restrict__ w2, const float* __restrict__ w3,
                         bf16* __restrict__ o0, bf16* __restrict__ o1,
                         bf16* __restrict__ o2, bf16* __restrict__ o3) {
    __shared__ float t[64][65];
    const float* w; bf16* o;
    if (blockIdx.z == 0)      { w = w0; o = o0; }
    else if (blockIdx.z == 1) { w = w1; o = o1; }
    else if (blockIdx.z == 2) { w = w2; o = o2; }
    else                      { w = w3; o = o3; }
    int n0 = blockIdx.x * 64, k0 = blockIdx.y * 64;
    int tx = threadIdx.x & 63, ty = threadIdx.x >> 6;
    #pragma unroll
    for (int s = 0; s < 16; ++s) {
        int r = ty * 16 + s;
        t[r][tx] = w[(k0 + r) * 512 + n0 + tx];
    }
    __syncthreads();
    #pragma unroll
    for (int s = 0; s < 16; ++s) {
        int r = ty * 16 + s;
        o[(n0 + r) * 512 + k0 + tx] = (bf16)t[tx][r];
    }
}

__global__ void k_prep_er(const float* __restrict__ er, bf16* __restrict__ erB) {
    int i = blockIdx.x * 256 + threadIdx.x;
    int r = i >> 6;
    erB[i] = (r < 2048) ? (bf16)er[i] : (bf16)0.0f;
}

// ---------------- 64x64 GEMM tile core ----------------

__device__ __forceinline__ void gemm_tile_64x64(
    const bf16* __restrict__ A, const bf16* __restrict__ BT,
    int m0, int n0, bf16* la, bf16* lb, f32x4 (&acc)[4])
{
    const int tid = threadIdx.x;
    const int w = tid >> 6, lane = tid & 63;
    const int fm = lane & 15, fg = lane >> 4;
    const int srow = tid >> 2, sch = tid & 3;
    const int sph = sch ^ ((srow >> 1) & 3);
    for (int kt = 0; kt < 16; ++kt) {
        const int kb = kt * 32;
        __syncthreads();
        *reinterpret_cast<bf16x8*>(&la[srow * 32 + sph * 8]) =
            *reinterpret_cast<const bf16x8*>(&A[(m0 + srow) * 512 + kb + sch * 8]);
        *reinterpret_cast<bf16x8*>(&lb[srow * 32 + sph * 8]) =
            *reinterpret_cast<const bf16x8*>(&BT[(n0 + srow) * 512 + kb + sch * 8]);
        __syncthreads();
        const int ar = w * 16 + fm;
        bf16x8 af = *reinterpret_cast<const bf16x8*>(&la[ar * 32 + (fg ^ ((ar >> 1) & 3)) * 8]);
        #pragma unroll
        for (int c = 0; c < 4; ++c) {
            const int br = c * 16 + fm;
            bf16x8 bb = *reinterpret_cast<const bf16x8*>(&lb[br * 32 + (fg ^ ((br >> 1) & 3)) * 8]);
            acc[c] = MFMA(af, bb, acc[c]);
        }
    }
}

__global__ __launch_bounds__(256, 2) void k_gemm_qkv(
    const bf16* __restrict__ xb, const bf16* __restrict__ wqT,
    const bf16* __restrict__ wkT, const bf16* __restrict__ wvT,
    bf16* __restrict__ qo, bf16* __restrict__ ko, bf16* __restrict__ vTo)
{
    __shared__ bf16 la[64 * 32];
    __shared__ bf16 lb[64 * 32];
    const int m0 = blockIdx.x * 64, n0 = blockIdx.y * 64, z = blockIdx.z;
    const bf16* BT = (z == 0) ? wqT : (z == 1) ? wkT : wvT;
    f32x4 acc[4] = {};
    gemm_tile_64x64(xb, BT, m0, n0, la, lb, acc);
    const int w = threadIdx.x >> 6, lane = threadIdx.x & 63;
    const int fm = lane & 15, fg = lane >> 4;
    #pragma unroll
    for (int c = 0; c < 4; ++c)
        #pragma unroll
        for (int r = 0; r < 4; ++r) {
            const int m  = m0 + w * 16 + fg * 4 + r;
            const int nf = n0 + c * 16 + fm;
            const int b = m >> 11, tok = m & 2047;
            const int h = nf >> 6, d = nf & 63;
            const float v = acc[c][r];
            if (z == 0)      qo[((b * 8 + h) * 2048 + tok) * 64 + d] = (bf16)(v * 0.125f);
            else if (z == 1) ko[((b * 8 + h) * 2048 + tok) * 64 + d] = (bf16)v;
            else             vTo[((b * 8 + h) * 64 + d) * 2048 + tok] = (bf16)v;
        }
}

__global__ __launch_bounds__(256, 2) void k_gemm_out(
    const bf16* __restrict__ ao, const bf16* __restrict__ woT, float* __restrict__ out)
{
    __shared__ bf16 la[64 * 32];
    __shared__ bf16 lb[64 * 32];
    const int m0 = blockIdx.x * 64, n0 = blockIdx.y * 64;
    f32x4 acc[4] = {};
    gemm_tile_64x64(ao, woT, m0, n0, la, lb, acc);
    const int w = threadIdx.x >> 6, lane = threadIdx.x & 63;
    const int fm = lane & 15, fg = lane >> 4;
    #pragma unroll
    for (int c = 0; c < 4; ++c)
        #pragma unroll
        for (int r = 0; r < 4; ++r) {
            const int m  = m0 + w * 16 + fg * 4 + r;
            const int nf = n0 + c * 16 + fm;
            out[m * 512 + nf] = acc[c][r];
        }
}

// ---------------- split-K causal flash attention with relative bias ----------------
// grid (48, 16): s<16 -> qt=s, full tile, direct write; 16<=s<32 -> qt=s chunk0 (j 0..15);
// s>=32 -> qt=s-16 chunk1 (j 16..qt). 256 threads / 4 waves, wave owns 16 Q rows.
__global__ __launch_bounds__(256, 3) void k_attn(
    const bf16* __restrict__ qg, const bf16* __restrict__ kg,
    const bf16* __restrict__ vg, const bf16* __restrict__ erB,
    bf16* __restrict__ ao, bf16* __restrict__ opart, float* __restrict__ ml)
{
    __shared__ bf16 lk[64 * 64];       // K tile [j][d], swizzled
    __shared__ bf16 lv[64 * 64];       // V^T tile [d][j], swizzled
    __shared__ bf16 gt[4 * 128 * 20];  // per-wave G band [tr][colw], stride 20 (8B-aligned rows)
    __shared__ bf16 lp[64 * 64];       // P, swizzled

    const int s = blockIdx.x, bh = blockIdx.y;
    int qt, c, jstart, jend;
    if (s < 16)      { qt = s;      c = 0; jstart = 0;  jend = qt; }
    else if (s < 32) { qt = s;      c = 0; jstart = 0;  jend = 15; }
    else             { qt = s - 16; c = 1; jstart = 16; jend = qt; }
    const int i0 = qt * 64;
    const bf16* qp = qg + bh * 2048 * 64;
    const bf16* kp = kg + bh * 2048 * 64;
    const bf16* vp = vg + bh * 64 * 2048;

    const int tid = threadIdx.x;
    const int w = tid >> 6, lane = tid & 63;
    const int fm = lane & 15, fg = lane >> 4;

    const bf16x8 aq0 = *reinterpret_cast<const bf16x8*>(&qp[(i0 + w * 16 + fm) * 64 + fg * 8]);
    const bf16x8 aq1 = *reinterpret_cast<const bf16x8*>(&qp[(i0 + w * 16 + fm) * 64 + 32 + fg * 8]);

    const int srow = tid >> 3, sg = tid & 7, sph = sg ^ (srow & 7);

    // prefetch first K/V tile into registers
    bf16x8 pk[2], pv[2];
    {
        const int j0 = jstart * 64;
        #pragma unroll
        for (int t = 0; t < 2; ++t) {
            const int row = srow + t * 32;
            pk[t] = *reinterpret_cast<const bf16x8*>(&kp[(j0 + row) * 64 + sg * 8]);
            pv[t] = *reinterpret_cast<const bf16x8*>(&vp[row * 2048 + j0 + sg * 8]);
        }
    }

    f32x4 oacc[4] = {};
    float mrow[4] = { -1e30f, -1e30f, -1e30f, -1e30f };
    float lrow[4] = { 0.f, 0.f, 0.f, 0.f };
    bf16* gtw = gt + w * 2560;

    for (int jt = jstart; jt <= jend; ++jt) {
        const int j0 = jt * 64;
        __syncthreads();                       // prev iteration's readers done
        #pragma unroll
        for (int t = 0; t < 2; ++t) {
            const int row = srow + t * 32;
            *reinterpret_cast<bf16x8*>(&lk[row * 64 + sph * 8]) = pk[t];
            *reinterpret_cast<bf16x8*>(&lv[row * 64 + sph * 8]) = pv[t];
        }
        __syncthreads();
        if (jt < jend) {                       // prefetch next tile (hidden under compute)
            const int j0n = j0 + 64;
            #pragma unroll
            for (int t = 0; t < 2; ++t) {
                const int row = srow + t * 32;
                pk[t] = *reinterpret_cast<const bf16x8*>(&kp[(j0n + row) * 64 + sg * 8]);
                pv[t] = *reinterpret_cast<const bf16x8*>(&vp[row * 2048 + j0n + sg * 8]);
            }
        }

        // S = Q K^T
        f32x4 sa[4];
        #pragma unroll
        for (int cc = 0; cc < 4; ++cc) {
            const int br = cc * 16 + fm;
            bf16x8 b0 = *reinterpret_cast<const bf16x8*>(&lk[br * 64 + ((fg     ^ (br & 7)) * 8)]);
            bf16x8 b1 = *reinterpret_cast<const bf16x8*>(&lk[br * 64 + (((4+fg) ^ (br & 7)) * 8)]);
            f32x4 sv = {};
            sv = MFMA(aq0, b0, sv);
            sv = MFMA(aq1, b1, sv);
            sa[cc] = sv;
        }

        // G = Q ErBand^T; B-fragments straight from global (erB is L2-resident)
        const int m0e = 1984 - i0 + j0;
        const bf16* erp = erB + m0e * 64;
        #pragma unroll
        for (int half = 0; half < 2; ++half) {
            bf16x8 eb0[4], eb1[4];
            #pragma unroll
            for (int u = 0; u < 4; ++u) {
                const int tr = (half * 4 + u) * 16 + fm;
                eb0[u] = *reinterpret_cast<const bf16x8*>(&erp[tr * 64 + fg * 8]);
                eb1[u] = *reinterpret_cast<const bf16x8*>(&erp[tr * 64 + 32 + fg * 8]);
            }
            #pragma unroll
            for (int u = 0; u < 4; ++u) {
                const int tr = (half * 4 + u) * 16 + fm;
                f32x4 g = {};
                g = MFMA(aq0, eb0[u], g);
                g = MFMA(aq1, eb1[u], g);
                bf16x4 gb = { (bf16)g[0], (bf16)g[1], (bf16)g[2], (bf16)g[3] };
                *reinterpret_cast<bf16x4*>(&gtw[tr * 20 + fg * 4]) = gb;  // same-wave region
            }
        }

        // rel gather + causal mask + tile row-max
        const int dmax = i0 - j0;
        float mtile[4] = { -3e38f, -3e38f, -3e38f, -3e38f };
        #pragma unroll
        for (int cc = 0; cc < 4; ++cc)
            #pragma unroll
            for (int r = 0; r < 4; ++r) {
                const int cw = fg * 4 + r;         // col within wave's gt
                const int il = w * 16 + cw;
                const int jl = cc * 16 + fm;
                float sv = sa[cc][r] + (float)gtw[(63 - il + jl) * 20 + cw];
                if (jl - il > dmax) sv = -3e38f;
                sa[cc][r] = sv;
                mtile[r] = fmaxf(mtile[r], sv);
            }
        float fac[4];
        #pragma unroll
        for (int r = 0; r < 4; ++r) {
            float v = mtile[r];
            v = fmaxf(v, __shfl_xor(v, 1, 64));
            v = fmaxf(v, __shfl_xor(v, 2, 64));
            v = fmaxf(v, __shfl_xor(v, 4, 64));
            v = fmaxf(v, __shfl_xor(v, 8, 64));
            const float mn = fmaxf(mrow[r], v);
            fac[r] = __expf(mrow[r] - mn);
            mrow[r] = mn;
        }
        float rs[4] = { 0.f, 0.f, 0.f, 0.f };
        #pragma unroll
        for (int cc = 0; cc < 4; ++cc)
            #pragma unroll
            for (int r = 0; r < 4; ++r) {
                const float p = __expf(sa[cc][r] - mrow[r]);
                rs[r] += p;
                const int il = w * 16 + fg * 4 + r;
                const int jl = cc * 16 + fm;
                lp[il * 64 + ((((jl >> 3) ^ (il & 7)) << 3) | (jl & 7))] = (bf16)p;
            }
        #pragma unroll
        for (int r = 0; r < 4; ++r) {
            float v = rs[r];
            v += __shfl_xor(v, 1, 64);
            v += __shfl_xor(v, 2, 64);
            v += __shfl_xor(v, 4, 64);
            v += __shfl_xor(v, 8, 64);
            lrow[r] = lrow[r] * fac[r] + v;
        }
        #pragma unroll
        for (int df = 0; df < 4; ++df)
            #pragma unroll
            for (int r = 0; r < 4; ++r)
                oacc[df][r] *= fac[r];
        // O += P V
        const int ar = w * 16 + fm;
        bf16x8 ap0 = *reinterpret_cast<const bf16x8*>(&lp[ar * 64 + ((fg     ^ (ar & 7)) * 8)]);
        bf16x8 ap1 = *reinterpret_cast<const bf16x8*>(&lp[ar * 64 + (((4+fg) ^ (ar & 7)) * 8)]);
        #pragma unroll
        for (int df = 0; df < 4; ++df) {
            const int dr = df * 16 + fm;
            bf16x8 b0 = *reinterpret_cast<const bf16x8*>(&lv[dr * 64 + ((fg     ^ (dr & 7)) * 8)]);
            bf16x8 b1 = *reinterpret_cast<const bf16x8*>(&lv[dr * 64 + (((4+fg) ^ (dr & 7)) * 8)]);
            oacc[df] = MFMA(ap0, b0, oacc[df]);
            oacc[df] = MFMA(ap1, b1, oacc[df]);
        }
    }

    if (s < 16) {
        // single-chunk tiles: normalize and write ao directly
        const int b = bh >> 3, h = bh & 7;
        #pragma unroll
        for (int df = 0; df < 4; ++df)
            #pragma unroll
            for (int r = 0; r < 4; ++r) {
                const int i = i0 + w * 16 + fg * 4 + r;
                const int d = df * 16 + fm;
                ao[(b * 2048 + i) * 512 + h * 64 + d] = (bf16)(oacc[df][r] / lrow[r]);
            }
    } else {
        // write unnormalized partial + (m,l)
        const int slot = (bh * 16 + (qt - 16)) * 2 + c;
        #pragma unroll
        for (int df = 0; df < 4; ++df)
            #pragma unroll
            for (int r = 0; r < 4; ++r) {
                const int il = w * 16 + fg * 4 + r;
                const int d = df * 16 + fm;
                opart[slot * 4096 + il * 64 + d] = (bf16)oacc[df][r];
            }
        if (fm == 0) {
            #pragma unroll
            for (int r = 0; r < 4; ++r) {
                const int il = w * 16 + fg * 4 + r;
                ml[slot * 128 + il] = mrow[r];
                ml[slot * 128 + 64 + il] = lrow[r];
            }
        }
    }
}

// combine the 2 chunks of each qt>=16 tile
__global__ void k_combine(const bf16* __restrict__ opart, const float* __restrict__ ml,
                          bf16* __restrict__ ao) {
    const int qt = 16 + blockIdx.x;          // 16..31
    const int bh = blockIdx.y;
    const int slot0 = (bh * 16 + blockIdx.x) * 2;
    const int t = threadIdx.x;
    const int row = t >> 2, cb = (t & 3) * 16;
    const float m0 = ml[slot0 * 128 + row],       l0 = ml[slot0 * 128 + 64 + row];
    const float m1 = ml[(slot0 + 1) * 128 + row], l1 = ml[(slot0 + 1) * 128 + 64 + row];
    const float M = fmaxf(m0, m1);
    const float s0 = __expf(m0 - M), s1 = __expf(m1 - M);
    const float inv = 1.0f / (l0 * s0 + l1 * s1);
    const int b = bh >> 3, h = bh & 7;
    const int i = qt * 64 + row;
    bf16* dst = ao + (b * 2048 + i) * 512 + h * 64 + cb;
    const bf16* p0 = opart + slot0 * 4096 + row * 64 + cb;
    const bf16* p1 = opart + (slot0 + 1) * 4096 + row * 64 + cb;
    #pragma unroll
    for (int half = 0; half < 2; ++half) {
        bf16x8 a0 = *reinterpret_cast<const bf16x8*>(p0 + half * 8);
        bf16x8 a1 = *reinterpret_cast<const bf16x8*>(p1 + half * 8);
        bf16x8 o;
        #pragma unroll
        for (int e = 0; e < 8; ++e)
            o[e] = (bf16)(((float)a0[e] * s0 + (float)a1[e] * s1) * inv);
        *reinterpret_cast<bf16x8*>(dst + half * 8) = o;
    }
}

// ---------------- host launcher ----------------

extern "C" void kernel_launch(void* const* d_in, const int* in_sizes, int n_in,
                              void* d_out, int out_size, void* d_ws, size_t ws_size,
                              hipStream_t stream) {
    (void)in_sizes; (void)n_in; (void)out_size; (void)ws_size;
    const float* x  = (const float*)d_in[0];
    const float* Wq = (const float*)d_in[1];
    const float* Wk = (const float*)d_in[2];
    const float* Wv = (const float*)d_in[3];
    const float* Wo = (const float*)d_in[4];
    const float* Er = (const float*)d_in[5];
    float* out = (float*)d_out;

    char* ws = (char*)d_ws;
    bf16* xb  = (bf16*)(ws);                  // 4 MB; dead after qkv gemm -> reused as opart
    bf16* wqT = (bf16*)(ws + 4194304);        // 512 KB; dead after qkv gemm -> reused as ml
    bf16* wkT = (bf16*)(ws + 4718592);
    bf16* wvT = (bf16*)(ws + 5242880);
    bf16* woT = (bf16*)(ws + 5767168);
    bf16* erB = (bf16*)(ws + 6291456);        // 2176*64*2
    bf16* q   = (bf16*)(ws + 6569984);
    bf16* k   = (bf16*)(ws + 10764288);
    bf16* vT  = (bf16*)(ws + 14958592);
    bf16* ao  = (bf16*)(ws + 19152896);       // end 23,347,200 B

    bf16*  opart = (bf16*)ws;                 // [512][64][64] bf16 = 4 MB (overlays xb)
    float* ml    = (float*)(ws + 4194304);    // [512][128] f32 = 256 KB (overlays wqT)

    k_cast_x<<<dim3(2048), dim3(256), 0, stream>>>(x, xb);
    k_prep_w<<<dim3(8, 8, 4), dim3(256), 0, stream>>>(Wq, Wk, Wv, Wo, wqT, wkT, wvT, woT);
    k_prep_er<<<dim3(544), dim3(256), 0, stream>>>(Er, erB);
    k_gemm_qkv<<<dim3(64, 8, 3), dim3(256), 0, stream>>>(xb, wqT, wkT, wvT, q, k, vT);
    k_attn<<<dim3(48, 16), dim3(256), 0, stream>>>(q, k, vT, erB, ao, opart, ml);
    k_combine<<<dim3(16, 16), dim3(256), 0, stream>>>(opart, ml, ao);
    k_gemm_out<<<dim3(64, 8), dim3(256), 0, stream>>>(ao, woT, out);
}

// Round 7
// 213.889 us; speedup vs baseline: 1.0072x; 1.0072x over previous
//
#include <hip/hip_runtime.h>
#include <stdint.h>

typedef __bf16 bf16;
typedef __bf16 bf16x4 __attribute__((ext_vector_type(4)));
typedef __bf16 bf16x8 __attribute__((ext_vector_type(8)));
typedef float f32x4 __attribute__((ext_vector_type(4)));

#define MFMA(a, b, c) __builtin_amdgcn_mfma_f32_16x16x32_bf16(a, b, c, 0, 0, 0)

// ---------------- prep kernels ----------------

__global__ void k_cast_x(const float* __restrict__ x, bf16* __restrict__ xb) {
    int i = (blockIdx.x * 256 + threadIdx.x) * 4;
    float4 v = *reinterpret_cast<const float4*>(x + i);
    bf16x4 o = { (bf16)v.x, (bf16)v.y, (bf16)v.z, (bf16)v.w };
    *reinterpret_cast<bf16x4*>(xb + i) = o;
}

__global__ void k_prep_w(const float* __restrict__ w0, const float* __restrict__ w1,
                         const float* __restrict__ w2, const float* __restrict__ w3,
                         bf16* __restrict__ o0, bf16* __restrict__ o1,
                         bf16* __restrict__ o2, bf16* __restrict__ o3) {
    __shared__ float t[64][65];
    const float* w; bf16* o;
    if (blockIdx.z == 0)      { w = w0; o = o0; }
    else if (blockIdx.z == 1) { w = w1; o = o1; }
    else if (blockIdx.z == 2) { w = w2; o = o2; }
    else                      { w = w3; o = o3; }
    int n0 = blockIdx.x * 64, k0 = blockIdx.y * 64;
    int tx = threadIdx.x & 63, ty = threadIdx.x >> 6;
    #pragma unroll
    for (int s = 0; s < 16; ++s) {
        int r = ty * 16 + s;
        t[r][tx] = w[(k0 + r) * 512 + n0 + tx];
    }
    __syncthreads();
    #pragma unroll
    for (int s = 0; s < 16; ++s) {
        int r = ty * 16 + s;
        o[(n0 + r) * 512 + k0 + tx] = (bf16)t[tx][r];
    }
}

__global__ void k_prep_er(const float* __restrict__ er, bf16* __restrict__ erB) {
    int i = blockIdx.x * 256 + threadIdx.x;
    int r = i >> 6;
    erB[i] = (r < 2048) ? (bf16)er[i] : (bf16)0.0f;
}

// ---------------- 64x64 GEMM tile core ----------------

__device__ __forceinline__ void gemm_tile_64x64(
    const bf16* __restrict__ A, const bf16* __restrict__ BT,
    int m0, int n0, bf16* la, bf16* lb, f32x4 (&acc)[4])
{
    const int tid = threadIdx.x;
    const int w = tid >> 6, lane = tid & 63;
    const int fm = lane & 15, fg = lane >> 4;
    const int srow = tid >> 2, sch = tid & 3;
    const int sph = sch ^ ((srow >> 1) & 3);
    for (int kt = 0; kt < 16; ++kt) {
        const int kb = kt * 32;
        __syncthreads();
        *reinterpret_cast<bf16x8*>(&la[srow * 32 + sph * 8]) =
            *reinterpret_cast<const bf16x8*>(&A[(m0 + srow) * 512 + kb + sch * 8]);
        *reinterpret_cast<bf16x8*>(&lb[srow * 32 + sph * 8]) =
            *reinterpret_cast<const bf16x8*>(&BT[(n0 + srow) * 512 + kb + sch * 8]);
        __syncthreads();
        const int ar = w * 16 + fm;
        bf16x8 af = *reinterpret_cast<const bf16x8*>(&la[ar * 32 + (fg ^ ((ar >> 1) & 3)) * 8]);
        #pragma unroll
        for (int c = 0; c < 4; ++c) {
            const int br = c * 16 + fm;
            bf16x8 bb = *reinterpret_cast<const bf16x8*>(&lb[br * 32 + (fg ^ ((br >> 1) & 3)) * 8]);
            acc[c] = MFMA(af, bb, acc[c]);
        }
    }
}

__global__ __launch_bounds__(256, 2) void k_gemm_qkv(
    const bf16* __restrict__ xb, const bf16* __restrict__ wqT,
    const bf16* __restrict__ wkT, const bf16* __restrict__ wvT,
    bf16* __restrict__ qo, bf16* __restrict__ ko, bf16* __restrict__ vTo)
{
    __shared__ bf16 la[64 * 32];
    __shared__ bf16 lb[64 * 32];
    const int m0 = blockIdx.x * 64, n0 = blockIdx.y * 64, z = blockIdx.z;
    const bf16* BT = (z == 0) ? wqT : (z == 1) ? wkT : wvT;
    f32x4 acc[4] = {};
    gemm_tile_64x64(xb, BT, m0, n0, la, lb, acc);
    const int w = threadIdx.x >> 6, lane = threadIdx.x & 63;
    const int fm = lane & 15, fg = lane >> 4;
    #pragma unroll
    for (int c = 0; c < 4; ++c)
        #pragma unroll
        for (int r = 0; r < 4; ++r) {
            const int m  = m0 + w * 16 + fg * 4 + r;
            const int nf = n0 + c * 16 + fm;
            const int b = m >> 11, tok = m & 2047;
            const int h = nf >> 6, d = nf & 63;
            const float v = acc[c][r];
            if (z == 0)      qo[((b * 8 + h) * 2048 + tok) * 64 + d] = (bf16)(v * 0.125f);
            else if (z == 1) ko[((b * 8 + h) * 2048 + tok) * 64 + d] = (bf16)v;
            else             vTo[((b * 8 + h) * 64 + d) * 2048 + tok] = (bf16)v;
        }
}

__global__ __launch_bounds__(256, 2) void k_gemm_out(
    const bf16* __restrict__ ao, const bf16* __restrict__ woT, float* __restrict__ out)
{
    __shared__ bf16 la[64 * 32];
    __shared__ bf16 lb[64 * 32];
    const int m0 = blockIdx.x * 64, n0 = blockIdx.y * 64;
    f32x4 acc[4] = {};
    gemm_tile_64x64(ao, woT, m0, n0, la, lb, acc);
    const int w = threadIdx.x >> 6, lane = threadIdx.x & 63;
    const int fm = lane & 15, fg = lane >> 4;
    #pragma unroll
    for (int c = 0; c < 4; ++c)
        #pragma unroll
        for (int r = 0; r < 4; ++r) {
            const int m  = m0 + w * 16 + fg * 4 + r;
            const int nf = n0 + c * 16 + fm;
            out[m * 512 + nf] = acc[c][r];
        }
}

// ---------------- causal flash attention with relative bias, KVBLK=128 ----------------
// grid (32, 16). qt chosen by bh parity so round-robin CU pairs sum to ~17 iterations.
// 256 threads / 4 waves; wave w owns Q rows [16w,16w+16) of the 64-row tile.
// Per j-iteration covers 128 K/V columns: niter(qt) = qt/2 + 1.
__global__ __launch_bounds__(256, 2) void k_attn(
    const bf16* __restrict__ qg, const bf16* __restrict__ kg,
    const bf16* __restrict__ vg, const bf16* __restrict__ erB,
    bf16* __restrict__ ao)
{
    __shared__ bf16 lk[128 * 64];      // K tile [j][d], 8-chunk XOR swizzle
    __shared__ bf16 lv[64 * 128];      // V^T tile [d][j], 16-chunk XOR swizzle
    __shared__ bf16 gt[4 * 192 * 20];  // per-wave G band [tr][il_local], stride 20
    __shared__ bf16 lp[64 * 128];      // P [il][jl], 16-chunk XOR swizzle

    const int bh = blockIdx.y;
    const int qt = (bh & 8) ? blockIdx.x : (31 - blockIdx.x);
    const int i0 = qt * 64;
    const bf16* qp = qg + bh * 2048 * 64;
    const bf16* kp = kg + bh * 2048 * 64;
    const bf16* vp = vg + bh * 64 * 2048;

    const int tid = threadIdx.x;
    const int w = tid >> 6, lane = tid & 63;
    const int fm = lane & 15, fg = lane >> 4;

    const bf16x8 aq0 = *reinterpret_cast<const bf16x8*>(&qp[(i0 + w * 16 + fm) * 64 + fg * 8]);
    const bf16x8 aq1 = *reinterpret_cast<const bf16x8*>(&qp[(i0 + w * 16 + fm) * 64 + 32 + fg * 8]);

    // prefetch first K/V tile (128 rows of K, 64 d-rows x 128 j of V^T)
    bf16x8 pk[4], pv[4];
    #pragma unroll
    for (int t = 0; t < 4; ++t) {
        const int cid = t * 256 + tid;
        pk[t] = *reinterpret_cast<const bf16x8*>(&kp[(cid >> 3) * 64 + (cid & 7) * 8]);
        pv[t] = *reinterpret_cast<const bf16x8*>(&vp[(cid >> 4) * 2048 + (cid & 15) * 8]);
    }

    f32x4 oacc[4] = {};
    float mrow[4] = { -1e30f, -1e30f, -1e30f, -1e30f };
    float lrow[4] = { 0.f, 0.f, 0.f, 0.f };
    bf16* gtw = gt + w * 3840;

    for (int j0 = 0; j0 <= i0; j0 += 128) {
        __syncthreads();                       // prev iteration's readers done
        #pragma unroll
        for (int t = 0; t < 4; ++t) {
            const int cid = t * 256 + tid;
            const int krow = cid >> 3, kg2 = cid & 7;
            *reinterpret_cast<bf16x8*>(&lk[krow * 64 + (kg2 ^ (krow & 7)) * 8]) = pk[t];
            const int vrow = cid >> 4, vg2 = cid & 15;
            *reinterpret_cast<bf16x8*>(&lv[vrow * 128 + (vg2 ^ (vrow & 15)) * 8]) = pv[t];
        }
        __syncthreads();
        if (j0 + 128 <= i0) {                  // prefetch next tile under compute
            const int j0n = j0 + 128;
            #pragma unroll
            for (int t = 0; t < 4; ++t) {
                const int cid = t * 256 + tid;
                pk[t] = *reinterpret_cast<const bf16x8*>(&kp[(j0n + (cid >> 3)) * 64 + (cid & 7) * 8]);
                pv[t] = *reinterpret_cast<const bf16x8*>(&vp[(cid >> 4) * 2048 + j0n + (cid & 15) * 8]);
            }
        }

        // S = Q K^T  (wave strip 16x128)
        f32x4 sa[8];
        #pragma unroll
        for (int cc = 0; cc < 8; ++cc) {
            const int br = cc * 16 + fm;
            bf16x8 b0 = *reinterpret_cast<const bf16x8*>(&lk[br * 64 + ((fg     ^ (br & 7)) * 8)]);
            bf16x8 b1 = *reinterpret_cast<const bf16x8*>(&lk[br * 64 + (((4+fg) ^ (br & 7)) * 8)]);
            f32x4 sv = {};
            sv = MFMA(aq0, b0, sv);
            sv = MFMA(aq1, b1, sv);
            sa[cc] = sv;
        }

        // G = Q ErBand^T over 192 band rows (191 used); er B-frags direct from global (L2)
        const int m0e = 1984 - i0 + j0;
        const bf16* erp = erB + m0e * 64;
        #pragma unroll
        for (int u = 0; u < 12; ++u) {
            const int tr = u * 16 + fm;
            bf16x8 e0 = *reinterpret_cast<const bf16x8*>(&erp[tr * 64 + fg * 8]);
            bf16x8 e1 = *reinterpret_cast<const bf16x8*>(&erp[tr * 64 + 32 + fg * 8]);
            f32x4 g = {};
            g = MFMA(aq0, e0, g);
            g = MFMA(aq1, e1, g);
            bf16x4 gb = { (bf16)g[0], (bf16)g[1], (bf16)g[2], (bf16)g[3] };
            *reinterpret_cast<bf16x4*>(&gtw[tr * 20 + fg * 4]) = gb;   // same-wave region
        }

        // rel gather + causal mask + tile row-max
        const int dmax = i0 - j0;
        float mtile[4] = { -3e38f, -3e38f, -3e38f, -3e38f };
        #pragma unroll
        for (int cc = 0; cc < 8; ++cc)
            #pragma unroll
            for (int r = 0; r < 4; ++r) {
                const int cw = fg * 4 + r;
                const int il = w * 16 + cw;
                const int jl = cc * 16 + fm;
                float sv = sa[cc][r] + (float)gtw[(63 - il + jl) * 20 + cw];
                if (jl - il > dmax) sv = -3e38f;
                sa[cc][r] = sv;
                mtile[r] = fmaxf(mtile[r], sv);
            }
        float fac[4];
        #pragma unroll
        for (int r = 0; r < 4; ++r) {
            float v = mtile[r];
            v = fmaxf(v, __shfl_xor(v, 1, 64));
            v = fmaxf(v, __shfl_xor(v, 2, 64));
            v = fmaxf(v, __shfl_xor(v, 4, 64));
            v = fmaxf(v, __shfl_xor(v, 8, 64));
            const float mn = fmaxf(mrow[r], v);
            fac[r] = __expf(mrow[r] - mn);
            mrow[r] = mn;
        }
        float rs[4] = { 0.f, 0.f, 0.f, 0.f };
        #pragma unroll
        for (int cc = 0; cc < 8; ++cc)
            #pragma unroll
            for (int r = 0; r < 4; ++r) {
                const float p = __expf(sa[cc][r] - mrow[r]);
                rs[r] += p;
                const int il = w * 16 + fg * 4 + r;
                const int jl = cc * 16 + fm;
                lp[il * 128 + (((jl >> 3) ^ (il & 15)) << 3) + (jl & 7)] = (bf16)p;
            }
        #pragma unroll
        for (int r = 0; r < 4; ++r) {
            float v = rs[r];
            v += __shfl_xor(v, 1, 64);
            v += __shfl_xor(v, 2, 64);
            v += __shfl_xor(v, 4, 64);
            v += __shfl_xor(v, 8, 64);
            lrow[r] = lrow[r] * fac[r] + v;
        }
        #pragma unroll
        for (int df = 0; df < 4; ++df)
            #pragma unroll
            for (int r = 0; r < 4; ++r)
                oacc[df][r] *= fac[r];
        // O += P V  (P in LDS, same-wave rows; V^T from LDS)
        const int ar = w * 16 + fm;
        bf16x8 ap[4];
        #pragma unroll
        for (int ks = 0; ks < 4; ++ks)
            ap[ks] = *reinterpret_cast<const bf16x8*>(&lp[ar * 128 + (((ks * 4 + fg) ^ (ar & 15)) * 8)]);
        #pragma unroll
        for (int df = 0; df < 4; ++df) {
            const int dr = df * 16 + fm;
            #pragma unroll
            for (int ks = 0; ks < 4; ++ks) {
                bf16x8 bb = *reinterpret_cast<const bf16x8*>(&lv[dr * 128 + (((ks * 4 + fg) ^ (dr & 15)) * 8)]);
                oacc[df] = MFMA(ap[ks], bb, oacc[df]);
            }
        }
    }

    // epilogue: ao[b][i][h*64+d]
    const int b = bh >> 3, h = bh & 7;
    #pragma unroll
    for (int df = 0; df < 4; ++df)
        #pragma unroll
        for (int r = 0; r < 4; ++r) {
            const int i = i0 + w * 16 + fg * 4 + r;
            const int d = df * 16 + fm;
            ao[(b * 2048 + i) * 512 + h * 64 + d] = (bf16)(oacc[df][r] / lrow[r]);
        }
}

// ---------------- host launcher ----------------

extern "C" void kernel_launch(void* const* d_in, const int* in_sizes, int n_in,
                              void* d_out, int out_size, void* d_ws, size_t ws_size,
                              hipStream_t stream) {
    (void)in_sizes; (void)n_in; (void)out_size; (void)ws_size;
    const float* x  = (const float*)d_in[0];
    const float* Wq = (const float*)d_in[1];
    const float* Wk = (const float*)d_in[2];
    const float* Wv = (const float*)d_in[3];
    const float* Wo = (const float*)d_in[4];
    const float* Er = (const float*)d_in[5];
    float* out = (float*)d_out;

    char* ws = (char*)d_ws;
    bf16* xb  = (bf16*)(ws);                  // 4096*512        = 4,194,304 B
    bf16* wqT = (bf16*)(ws + 4194304);
    bf16* wkT = (bf16*)(ws + 4718592);
    bf16* wvT = (bf16*)(ws + 5242880);
    bf16* woT = (bf16*)(ws + 5767168);
    bf16* erB = (bf16*)(ws + 6291456);        // 2176*64*2
    bf16* q   = (bf16*)(ws + 6569984);
    bf16* k   = (bf16*)(ws + 10764288);
    bf16* vT  = (bf16*)(ws + 14958592);
    bf16* ao  = (bf16*)(ws + 19152896);       // end 23,347,200 B

    k_cast_x<<<dim3(2048), dim3(256), 0, stream>>>(x, xb);
    k_prep_w<<<dim3(8, 8, 4), dim3(256), 0, stream>>>(Wq, Wk, Wv, Wo, wqT, wkT, wvT, woT);
    k_prep_er<<<dim3(544), dim3(256), 0, stream>>>(Er, erB);
    k_gemm_qkv<<<dim3(64, 8, 3), dim3(256), 0, stream>>>(xb, wqT, wkT, wvT, q, k, vT);
    k_attn<<<dim3(32, 16), dim3(256), 0, stream>>>(q, k, vT, erB, ao);
    k_gemm_out<<<dim3(64, 8), dim3(256), 0, stream>>>(ao, woT, out);
}